// Round 1
// baseline (1595.597 us; speedup 1.0000x reference)
//
#include <hip/hip_runtime.h>

#define K_DIM 4096
#define N_DIM 11008
#define M_DIM 8192
#define BM 128
#define BN 128
#define BK 32

typedef __bf16 bf16x8_t __attribute__((ext_vector_type(8)));
typedef float f32x4_t __attribute__((ext_vector_type(4)));

#define GLD_LDS16(g, l)                                                        \
  __builtin_amdgcn_global_load_lds(                                            \
      (const __attribute__((address_space(1))) void*)(g),                      \
      (__attribute__((address_space(3))) void*)(l), 16, 0, 0)

// ---------------------------------------------------------------------------
// Kernel 1: unpack int4 + dequant (s*q + b) -> bf16 W (N_DIM x K_DIM, K-contig)
// one thread per packed word (8 nibbles -> 16B store)
// ---------------------------------------------------------------------------
__global__ void dequant_w(const int* __restrict__ wp, const float* __restrict__ sc,
                          const float* __restrict__ bg, __bf16* __restrict__ W) {
  const int tid = blockIdx.x * 256 + threadIdx.x;  // < 11008*512
  const unsigned w = (unsigned)wp[tid];
  const int row = tid >> 9;       // /512
  const int word = tid & 511;
  const int g = word >> 4;        // group = (word*8)/128
  const float s = sc[row * 32 + g];
  const float b = bg[row * 32 + g];
  bf16x8_t v;
#pragma unroll
  for (int i = 0; i < 8; ++i)
    v[i] = (__bf16)(s * (float)((w >> (4 * i)) & 15u) + b);
  ((bf16x8_t*)W)[tid] = v;
}

// ---------------------------------------------------------------------------
// Kernel 2: x fp32 -> bf16 (8 elems/thread)
// ---------------------------------------------------------------------------
__global__ void cvt_x(const float* __restrict__ X, __bf16* __restrict__ Xb) {
  const size_t t = (size_t)blockIdx.x * 256 + threadIdx.x;  // < 4194304
  const float4* s = ((const float4*)X) + 2 * t;
  const float4 f0 = s[0], f1 = s[1];
  bf16x8_t v;
  v[0] = (__bf16)f0.x; v[1] = (__bf16)f0.y; v[2] = (__bf16)f0.z; v[3] = (__bf16)f0.w;
  v[4] = (__bf16)f1.x; v[5] = (__bf16)f1.y; v[6] = (__bf16)f1.z; v[7] = (__bf16)f1.w;
  ((bf16x8_t*)Xb)[t] = v;
}

// ---------------------------------------------------------------------------
// Kernel 3: bf16 GEMM-BT (m97 structure).  C[M,N] = A[M,K] * W[N,K]^T + bias
// 128x128x32 tile, 256 thr = 4 waves (2x2), each wave 64x64 via 4x4 MFMA
// 16x16x32.  AMODE 0: A pre-converted bf16, global_load_lds staging.
// AMODE 1: A fp32, fused cvt through registers into LDS.
// ---------------------------------------------------------------------------
template <int AMODE>
__launch_bounds__(256)
__global__ void qgemm(const __bf16* __restrict__ Ab, const float* __restrict__ Af,
                      const __bf16* __restrict__ Bw, const float* __restrict__ bias,
                      float* __restrict__ C) {
  __shared__ __bf16 As[BM * BK];  // 8 KB, [row][k] K-contig
  __shared__ __bf16 Bs[BN * BK];  // 8 KB

  const int tid = threadIdx.x;
  const int wave = tid >> 6;
  const int lane = tid & 63;
  const int l16 = lane & 15;
  const int quad = lane >> 4;
  const int wm = wave >> 1;  // 0..1
  const int wn = wave & 1;   // 0..1
  const int n0 = blockIdx.x * BN;
  const int m0 = blockIdx.y * BM;

  f32x4_t acc[4][4];
#pragma unroll
  for (int i = 0; i < 4; ++i)
#pragma unroll
    for (int j = 0; j < 4; ++j) acc[i][j] = (f32x4_t){0.f, 0.f, 0.f, 0.f};

  // staging maps: each wave fills 32 rows (2 instrs x 16 rows); lane L ->
  // row = base + (L>>2), kq = L&3 (8 bf16 = 16B per lane), LDS dest uniform
  // base + L*16 (wave-uniform base rule).
  const int skq = lane & 3;
  const __bf16* gB0 =
      Bw + (size_t)(n0 + wave * 32 + (lane >> 2)) * K_DIM + skq * 8;
  __bf16* lB0 = Bs + (wave * 32) * BK;

  const __bf16* gA0 =
      (AMODE == 0) ? Ab + (size_t)(m0 + wave * 32 + (lane >> 2)) * K_DIM + skq * 8
                   : nullptr;
  __bf16* lA0 = As + (wave * 32) * BK;

  // fused-cvt map (AMODE==1): thread t -> row t>>2 (+64), kq t&3
  const int ar = tid >> 2;
  const int akq = tid & 3;
  const float* gX0 =
      (AMODE == 1) ? Af + (size_t)(m0 + ar) * K_DIM + akq * 8 : nullptr;
  __bf16* lAf = As + ar * BK + akq * 8;

  for (int kt = 0; kt < K_DIM; kt += BK) {
    __syncthreads();  // previous iter's LDS reads done
    // ---- stage B (global -> LDS direct, 16B/lane) ----
    GLD_LDS16(gB0 + kt, lB0);
    GLD_LDS16(gB0 + kt + (size_t)16 * K_DIM, lB0 + 16 * BK);
    // ---- stage A ----
    if (AMODE == 0) {
      GLD_LDS16(gA0 + kt, lA0);
      GLD_LDS16(gA0 + kt + (size_t)16 * K_DIM, lA0 + 16 * BK);
    } else {
#pragma unroll
      for (int p = 0; p < 2; ++p) {
        const float4* s = (const float4*)(gX0 + (size_t)p * 64 * K_DIM + kt);
        const float4 f0 = s[0], f1 = s[1];
        bf16x8_t v;
        v[0] = (__bf16)f0.x; v[1] = (__bf16)f0.y;
        v[2] = (__bf16)f0.z; v[3] = (__bf16)f0.w;
        v[4] = (__bf16)f1.x; v[5] = (__bf16)f1.y;
        v[6] = (__bf16)f1.z; v[7] = (__bf16)f1.w;
        *(bf16x8_t*)(lAf + p * 64 * BK) = v;
      }
    }
    __syncthreads();  // staging visible (compiler drains vmcnt/lgkm)

    // ---- fragments + MFMA ----
    bf16x8_t fa[4], fb[4];
#pragma unroll
    for (int t = 0; t < 4; ++t)
      fa[t] = *(const bf16x8_t*)(As + (wm * 64 + t * 16 + l16) * BK + quad * 8);
#pragma unroll
    for (int t = 0; t < 4; ++t)
      fb[t] = *(const bf16x8_t*)(Bs + (wn * 64 + t * 16 + l16) * BK + quad * 8);
#pragma unroll
    for (int i = 0; i < 4; ++i)
#pragma unroll
      for (int j = 0; j < 4; ++j)
        acc[i][j] =
            __builtin_amdgcn_mfma_f32_16x16x32_bf16(fa[i], fb[j], acc[i][j], 0, 0, 0);
  }

  // ---- epilogue: C/D layout col=lane&15 (n), row=quad*4+r (m) ----
#pragma unroll
  for (int j = 0; j < 4; ++j) {
    const int n = n0 + wn * 64 + j * 16 + l16;
    const float bv = bias[n];
#pragma unroll
    for (int i = 0; i < 4; ++i) {
      const int mb = m0 + wm * 64 + i * 16 + quad * 4;
#pragma unroll
      for (int r = 0; r < 4; ++r)
        C[(size_t)(mb + r) * N_DIM + n] = acc[i][j][r] + bv;
    }
  }
}

// ---------------------------------------------------------------------------
// Safety-net: naive fp32 kernel (no workspace needed). One thread per output.
// ---------------------------------------------------------------------------
__global__ void qgemm_naive(const float* __restrict__ X, const int* __restrict__ WP,
                            const float* __restrict__ S, const float* __restrict__ BG,
                            const float* __restrict__ bias, float* __restrict__ C) {
  const int n = blockIdx.x * 256 + threadIdx.x;  // < 11008
  const int m = blockIdx.y;                      // < 8192
  const float* x = X + (size_t)m * K_DIM;
  float acc = 0.f;
  for (int g = 0; g < 32; ++g) {
    const float s = S[n * 32 + g];
    const float b = BG[n * 32 + g];
    for (int wd = 0; wd < 16; ++wd) {
      const unsigned w = (unsigned)WP[n * 512 + g * 16 + wd];
      const int kb = g * 128 + wd * 8;
#pragma unroll
      for (int i = 0; i < 8; ++i)
        acc += (s * (float)((w >> (4 * i)) & 15u) + b) * x[kb + i];
    }
  }
  C[(size_t)m * N_DIM + n] = acc + bias[n];
}

extern "C" void kernel_launch(void* const* d_in, const int* in_sizes, int n_in,
                              void* d_out, int out_size, void* d_ws, size_t ws_size,
                              hipStream_t stream) {
  const float* X = (const float*)d_in[0];
  const int* WP = (const int*)d_in[1];
  const float* S = (const float*)d_in[2];
  const float* BG = (const float*)d_in[3];
  const float* BIAS = (const float*)d_in[4];
  float* C = (float*)d_out;

  const size_t needW = (size_t)N_DIM * K_DIM * 2;  // 90,177,536 B
  const size_t needX = (size_t)M_DIM * K_DIM * 2;  // 67,108,864 B

  if (ws_size >= needW + needX) {
    __bf16* W = (__bf16*)d_ws;
    __bf16* Xb = (__bf16*)((char*)d_ws + needW);
    dequant_w<<<(N_DIM * 512) / 256, 256, 0, stream>>>(WP, S, BG, W);
    cvt_x<<<(M_DIM * K_DIM) / (256 * 8), 256, 0, stream>>>(X, Xb);
    qgemm<0><<<dim3(N_DIM / BN, M_DIM / BM), 256, 0, stream>>>(Xb, nullptr, W, BIAS, C);
  } else if (ws_size >= needW) {
    __bf16* W = (__bf16*)d_ws;
    dequant_w<<<(N_DIM * 512) / 256, 256, 0, stream>>>(WP, S, BG, W);
    qgemm<1><<<dim3(N_DIM / BN, M_DIM / BM), 256, 0, stream>>>(nullptr, X, W, BIAS, C);
  } else {
    qgemm_naive<<<dim3(N_DIM / 256, M_DIM), 256, 0, stream>>>(X, WP, S, BG, BIAS, C);
  }
}